// Round 1
// baseline (719.544 us; speedup 1.0000x reference)
//
#include <hip/hip_runtime.h>
#include <stdint.h>

// Problem constants (fixed by reference setup_inputs)
#define TOKENS 4096
#define HIDDEN 4096   // K
#define NQ     4096
#define NKV    1024
#define NTOT   6144   // NQ + 2*NKV
#define KPACK  512    // HIDDEN / 8

typedef __attribute__((ext_vector_type(8))) __bf16 bf16x8;
typedef __attribute__((ext_vector_type(8))) short short8v;
typedef __attribute__((ext_vector_type(4))) float floatx4;

// fp32 -> bf16 round-to-nearest-even (finite inputs only)
__device__ __forceinline__ short f2bf(float f) {
  union { float f; unsigned u; } v; v.f = f;
  unsigned r = v.u + 0x7fffu + ((v.u >> 16) & 1u);
  return (short)(r >> 16);
}

// async global->LDS, 16B per lane; LDS dest = wave-uniform base + lane*16
__device__ __forceinline__ void load_lds16(const void* g, void* l) {
  __builtin_amdgcn_global_load_lds((__attribute__((address_space(1))) void*)(g),
                                   (__attribute__((address_space(3))) void*)(l),
                                   16, 0, 0);
}

// ---------------------------------------------------------------------------
// Kernel 1: bucket tokens by delta index. grp[0..3]=start, grp[4..7]=count.
// Order within a bucket is irrelevant (each token's out-row written once).
// ---------------------------------------------------------------------------
__global__ __launch_bounds__(256) void prep_tokens(const int* __restrict__ idx,
                                                   int* __restrict__ token_list,
                                                   int* __restrict__ grp) {
  __shared__ int cnt[4], cur[4];
  const int tid = threadIdx.x;
  if (tid < 4) cnt[tid] = 0;
  __syncthreads();
  for (int t = tid; t < TOKENS; t += 256) {
    int d = idx[t];
    if ((unsigned)d < 4u) atomicAdd(&cnt[d], 1);
  }
  __syncthreads();
  if (tid == 0) {
    int s = 0;
    for (int d = 0; d < 4; d++) { cur[d] = s; grp[d] = s; grp[4 + d] = cnt[d]; s += cnt[d]; }
  }
  __syncthreads();
  for (int t = tid; t < TOKENS; t += 256) {
    int d = idx[t];
    if ((unsigned)d < 4u) {
      int p = atomicAdd(&cur[d], 1);
      token_list[p] = t;
    }
  }
}

// ---------------------------------------------------------------------------
// Kernel 2: x fp32 -> bf16 (row-major (TOKENS, HIDDEN)); 8 elems/thread.
// ---------------------------------------------------------------------------
__global__ __launch_bounds__(256) void cvt_x(const float* __restrict__ x,
                                             short* __restrict__ xb) {
  size_t g = (size_t)blockIdx.x * 256 + threadIdx.x;
  size_t i = g * 8;
  float4 a = ((const float4*)(x + i))[0];
  float4 b = ((const float4*)(x + i))[1];
  short8v o;
  o[0] = f2bf(a.x); o[1] = f2bf(a.y); o[2] = f2bf(a.z); o[3] = f2bf(a.w);
  o[4] = f2bf(b.x); o[5] = f2bf(b.y); o[6] = f2bf(b.z); o[7] = f2bf(b.w);
  *(short8v*)(xb + i) = o;
}

// ---------------------------------------------------------------------------
// Kernel 3: Wc[d] (NTOT x HIDDEN, bf16, B^T layout) = base + dequant(delta_d)
// GPTQ: W[k][n] = (q - (z+1)) * scale ; q packed 8-per-int32 along K,
// z packed 8-per-int32 along N.
// Block: 32 n-rows x 64 k (8 packs); thread t -> (n = t>>3, kp = t&7).
// base read is fully coalesced (loop over d reuses it); writes 16B/thread.
// ---------------------------------------------------------------------------
__global__ __launch_bounds__(256) void combine_w(
    const float* __restrict__ bw,
    const int* __restrict__ qwq, const int* __restrict__ qwk, const int* __restrict__ qwv,
    const int* __restrict__ qzq, const int* __restrict__ qzk, const int* __restrict__ qzv,
    const float* __restrict__ scq, const float* __restrict__ sck, const float* __restrict__ scv,
    short* __restrict__ wc) {
  const int tid = threadIdx.x;
  const int n  = blockIdx.y * 32 + (tid >> 3);
  const int kp = blockIdx.x * 8 + (tid & 7);
  const int k0 = kp * 8;

  const int* qw; const int* qz; const float* sc; int Ns, nn;
  if (n < NQ)            { qw = qwq; qz = qzq; sc = scq; Ns = NQ;  nn = n; }
  else if (n < NQ + NKV) { qw = qwk; qz = qzk; sc = sck; Ns = NKV; nn = n - NQ; }
  else                   { qw = qwv; qz = qzv; sc = scv; Ns = NKV; nn = n - NQ - NKV; }

  const float4* bp = (const float4*)(bw + (size_t)n * HIDDEN + k0);
  float4 b0 = bp[0], b1 = bp[1];
  float bv[8] = {b0.x, b0.y, b0.z, b0.w, b1.x, b1.y, b1.z, b1.w};

  const int zsh = (nn & 7) * 4;
#pragma unroll
  for (int d = 0; d < 4; d++) {
    unsigned q32 = (unsigned)qw[((size_t)d * KPACK + kp) * Ns + nn];
    int z = (int)(((unsigned)qz[d * (Ns >> 3) + (nn >> 3)] >> zsh) & 0xFu) + 1;
    float s = sc[d * Ns + nn];
    short8v o;
#pragma unroll
    for (int j = 0; j < 8; j++) {
      int q = (int)((q32 >> (4 * j)) & 0xFu);
      o[j] = f2bf((float)(q - z) * s + bv[j]);
    }
    *(short8v*)(wc + ((size_t)d * NTOT + n) * HIDDEN + k0) = o;
  }
}

// ---------------------------------------------------------------------------
// Kernel 4: grouped gathered GEMM. out[tok] = xb[tok] @ Wc[d]^T
// 128x128 tile, BK=32, 4 waves each owning a 64x64 quadrant (4x4 of
// 16x16x32 bf16 MFMA). A-rows gathered via token_list; global_load_lds
// width=16 staging (LDS layout contiguous in lane order -> no padding).
// grid: x = n-tile (48), y = d*32 + row-tile-slot (128); idle slots exit.
// ---------------------------------------------------------------------------
__global__ __launch_bounds__(256) void gemm_grouped(
    const short* __restrict__ xb, const short* __restrict__ wc,
    const int* __restrict__ token_list, const int* __restrict__ grp,
    float* __restrict__ out) {
  const int d   = blockIdx.y >> 5;
  const int rt  = blockIdx.y & 31;
  const int cnt = grp[4 + d];
  if (rt * 128 >= cnt) return;          // uniform across block: safe early-exit
  const int start = grp[d];
  const int n0 = blockIdx.x * 128;

  __shared__ __align__(16) short As[128 * 32];
  __shared__ __align__(16) short Bs[128 * 32];
  __shared__ int toks[128];

  const int tid = threadIdx.x;
  if (tid < 128) {
    int r = rt * 128 + tid;
    if (r >= cnt) r = cnt - 1;          // clamp tail (stores guarded below)
    toks[tid] = token_list[start + r];
  }
  __syncthreads();

  const int wave = tid >> 6;
  const int lane = tid & 63;

  // staging: 512 units of 16B (8 bf16); unit u -> row u>>2, k-seg u&3
  const int u0 = wave * 128 + lane;
  const int u1 = u0 + 64;
  const int rA0 = u0 >> 2, sA0 = u0 & 3;
  const int rA1 = u1 >> 2, sA1 = u1 & 3;

  const short* gA0 = xb + (size_t)toks[rA0] * HIDDEN + sA0 * 8;
  const short* gA1 = xb + (size_t)toks[rA1] * HIDDEN + sA1 * 8;
  const short* wrow = wc + ((size_t)d * NTOT + n0) * HIDDEN;
  const short* gB0 = wrow + (size_t)rA0 * HIDDEN + sA0 * 8;
  const short* gB1 = wrow + (size_t)rA1 * HIDDEN + sA1 * 8;
  short* lA0 = As + (size_t)u0 * 8 - (size_t)lane * 8;  // wave-uniform base
  short* lA1 = lA0 + 512;
  short* lB0 = Bs + (size_t)u0 * 8 - (size_t)lane * 8;
  short* lB1 = lB0 + 512;

  const int mrow = lane & 15;
  const int kq   = (lane >> 4) * 8;
  const int wm   = (wave >> 1) * 64;
  const int wn   = (wave & 1) * 64;

  floatx4 acc[4][4];
#pragma unroll
  for (int i = 0; i < 4; i++)
#pragma unroll
    for (int j = 0; j < 4; j++) acc[i][j] = (floatx4){0.f, 0.f, 0.f, 0.f};

  for (int k0 = 0; k0 < HIDDEN; k0 += 32) {
    load_lds16(gA0 + k0, lA0);
    load_lds16(gA1 + k0, lA1);
    load_lds16(gB0 + k0, lB0);
    load_lds16(gB1 + k0, lB1);
    __syncthreads();   // compiler drains vmcnt before barrier

    bf16x8 a[4], b[4];
#pragma unroll
    for (int i = 0; i < 4; i++)
      a[i] = *(const bf16x8*)(As + (wm + i * 16 + mrow) * 32 + kq);
#pragma unroll
    for (int j = 0; j < 4; j++)
      b[j] = *(const bf16x8*)(Bs + (wn + j * 16 + mrow) * 32 + kq);
#pragma unroll
    for (int i = 0; i < 4; i++)
#pragma unroll
      for (int j = 0; j < 4; j++)
        acc[i][j] = __builtin_amdgcn_mfma_f32_16x16x32_bf16(a[i], b[j], acc[i][j], 0, 0, 0);
    __syncthreads();
  }

  // epilogue: C/D layout col = lane&15, row = (lane>>4)*4 + reg
  const int rbase = (lane >> 4) * 4;
  const int coll  = lane & 15;
#pragma unroll
  for (int i = 0; i < 4; i++) {
#pragma unroll
    for (int r = 0; r < 4; r++) {
      int m = wm + i * 16 + rbase + r;
      if (rt * 128 + m < cnt) {
        float* orow = out + (size_t)toks[m] * NTOT + n0 + wn + coll;
#pragma unroll
        for (int j = 0; j < 4; j++) orow[j * 16] = acc[i][j][r];
      }
    }
  }
}

// ---------------------------------------------------------------------------
extern "C" void kernel_launch(void* const* d_in, const int* in_sizes, int n_in,
                              void* d_out, int out_size, void* d_ws, size_t ws_size,
                              hipStream_t stream) {
  const float* x   = (const float*)d_in[0];
  const float* bw  = (const float*)d_in[1];
  const int*   qwq = (const int*)d_in[2];
  const int*   qwk = (const int*)d_in[3];
  const int*   qwv = (const int*)d_in[4];
  const int*   qzq = (const int*)d_in[5];
  const int*   qzk = (const int*)d_in[6];
  const int*   qzv = (const int*)d_in[7];
  const float* scq = (const float*)d_in[8];
  const float* sck = (const float*)d_in[9];
  const float* scv = (const float*)d_in[10];
  const int*   idx = (const int*)d_in[11];
  float* out = (float*)d_out;

  // workspace layout (needs ~225 MB)
  char* ws = (char*)d_ws;
  short* xb = (short*)ws;                                       // 33,554,432 B
  short* wc = (short*)(ws + (size_t)33554432);                  // 201,326,592 B
  int* token_list = (int*)(ws + (size_t)33554432 + 201326592);  // 16,384 B
  int* grp = token_list + TOKENS;                               // 32 B

  prep_tokens<<<1, 256, 0, stream>>>(idx, token_list, grp);
  cvt_x<<<(TOKENS * HIDDEN) / (256 * 8), 256, 0, stream>>>(x, xb);
  dim3 gc(HIDDEN / 64, NTOT / 32);  // (64, 192)
  combine_w<<<gc, 256, 0, stream>>>(bw, qwq, qwk, qwv, qzq, qzk, qzv, scq, sck, scv, wc);
  dim3 gg(NTOT / 128, 4 * (TOKENS / 128));  // (48, 128)
  gemm_grouped<<<gg, 256, 0, stream>>>(xb, wc, token_list, grp, out);
}

// Round 2
// 709.057 us; speedup vs baseline: 1.0148x; 1.0148x over previous
//
#include <hip/hip_runtime.h>
#include <stdint.h>

// Problem constants (fixed by reference setup_inputs)
#define TOKENS 4096
#define HIDDEN 4096   // K
#define NQ     4096
#define NKV    1024
#define NTOT   6144   // NQ + 2*NKV
#define KPACK  512    // HIDDEN / 8
#define MAXTILES 36   // max sum_d ceil(cnt_d/128)

typedef __attribute__((ext_vector_type(8))) __bf16 bf16x8;
typedef __attribute__((ext_vector_type(8))) short short8v;
typedef __attribute__((ext_vector_type(4))) float floatx4;

// fp32 -> bf16 round-to-nearest-even (finite inputs only)
__device__ __forceinline__ short f2bf(float f) {
  union { float f; unsigned u; } v; v.f = f;
  unsigned r = v.u + 0x7fffu + ((v.u >> 16) & 1u);
  return (short)(r >> 16);
}
__device__ __forceinline__ float bf2f(short s) {
  union { float f; unsigned u; } v; v.u = ((unsigned)(unsigned short)s) << 16;
  return v.f;
}

// async global->LDS, 16B per lane; LDS dest = wave-uniform base + lane*16
__device__ __forceinline__ void load_lds16(const void* g, void* l) {
  __builtin_amdgcn_global_load_lds((__attribute__((address_space(1))) void*)(g),
                                   (__attribute__((address_space(3))) void*)(l),
                                   16, 0, 0);
}

// ---------------------------------------------------------------------------
// Kernel 1: bucket tokens by delta index + build compact tile table.
// grp[0..3]=start, grp[4..7]=count, grp[8]=n_tiles, grp[9..9+nt)=d|(rt<<2).
// ---------------------------------------------------------------------------
__global__ __launch_bounds__(256) void prep_tokens(const int* __restrict__ idx,
                                                   int* __restrict__ token_list,
                                                   int* __restrict__ grp) {
  __shared__ int cnt[4], cur[4];
  const int tid = threadIdx.x;
  if (tid < 4) cnt[tid] = 0;
  __syncthreads();
  for (int t = tid; t < TOKENS; t += 256) {
    int d = idx[t];
    if ((unsigned)d < 4u) atomicAdd(&cnt[d], 1);
  }
  __syncthreads();
  if (tid == 0) {
    int s = 0, nt = 0;
    for (int d = 0; d < 4; d++) {
      cur[d] = s; grp[d] = s; grp[4 + d] = cnt[d]; s += cnt[d];
      int tiles = (cnt[d] + 127) >> 7;
      for (int rt = 0; rt < tiles; rt++) grp[9 + nt++] = d | (rt << 2);
    }
    grp[8] = nt;
  }
  __syncthreads();
  for (int t = tid; t < TOKENS; t += 256) {
    int d = idx[t];
    if ((unsigned)d < 4u) {
      int p = atomicAdd(&cur[d], 1);
      token_list[p] = t;
    }
  }
}

// ---------------------------------------------------------------------------
// Kernel 2: x fp32 -> bf16 (row-major (TOKENS, HIDDEN)); 8 elems/thread.
// ---------------------------------------------------------------------------
__global__ __launch_bounds__(256) void cvt_x(const float* __restrict__ x,
                                             short* __restrict__ xb) {
  size_t g = (size_t)blockIdx.x * 256 + threadIdx.x;
  size_t i = g * 8;
  float4 a = ((const float4*)(x + i))[0];
  float4 b = ((const float4*)(x + i))[1];
  short8v o;
  o[0] = f2bf(a.x); o[1] = f2bf(a.y); o[2] = f2bf(a.z); o[3] = f2bf(a.w);
  o[4] = f2bf(b.x); o[5] = f2bf(b.y); o[6] = f2bf(b.z); o[7] = f2bf(b.w);
  *(short8v*)(xb + i) = o;
}

// ---------------------------------------------------------------------------
// Kernel 3: Wc[d] (NTOT x HIDDEN bf16, B^T layout) = base + dequant(delta_d).
// Block tile: 64 n x 64 k, all 4 d staged in LDS (n-major, stride 72 -> b128
// conflict-free), so base is read ONCE and all reads/writes are coalesced.
// ---------------------------------------------------------------------------
__global__ __launch_bounds__(256) void combine_w(
    const float* __restrict__ bw,
    const int* __restrict__ qwq, const int* __restrict__ qwk, const int* __restrict__ qwv,
    const int* __restrict__ qzq, const int* __restrict__ qzk, const int* __restrict__ qzv,
    const float* __restrict__ scq, const float* __restrict__ sck, const float* __restrict__ scv,
    short* __restrict__ wc) {
  __shared__ short tile[4][64][72];
  __shared__ float zs[4][64], ss[4][64];
  const int tid = threadIdx.x;
  const int n0  = blockIdx.y * 64;
  const int kp0 = blockIdx.x * 8;   // k0 = kp0*8

  const int* qw; const int* qz; const float* sc; int Ns, nb;
  if (n0 < NQ)            { qw = qwq; qz = qzq; sc = scq; Ns = NQ;  nb = n0; }
  else if (n0 < NQ + NKV) { qw = qwk; qz = qzk; sc = sck; Ns = NKV; nb = n0 - NQ; }
  else                    { qw = qwv; qz = qzv; sc = scv; Ns = NKV; nb = n0 - NQ - NKV; }

  // zeros + scales: tid -> (d = tid>>6, n = tid&63)
  {
    int d = tid >> 6, n = tid & 63;
    int nn = nb + n;
    int z = (int)(((unsigned)qz[d * (Ns >> 3) + (nn >> 3)] >> ((nn & 7) * 4)) & 0xFu);
    zs[d][n] = (float)(z + 1);
    ss[d][n] = sc[d * Ns + nn];
  }
  __syncthreads();

  // phase A: unpack qw (coalesced along n) -> LDS bf16 tiles
#pragma unroll
  for (int d = 0; d < 4; d++) {
#pragma unroll
    for (int p = 0; p < 2; p++) {
      int i  = tid + p * 256;
      int kp = i >> 6, n = i & 63;
      unsigned q32 = (unsigned)qw[((size_t)d * KPACK + kp0 + kp) * Ns + nb + n];
      float z = zs[d][n], s = ss[d][n];
      short8v o;
#pragma unroll
      for (int j = 0; j < 8; j++)
        o[j] = f2bf(((float)((q32 >> (4 * j)) & 0xFu) - z) * s);
      *(short8v*)&tile[d][n][kp * 8] = o;
    }
  }
  __syncthreads();

  // phase B: read base once, add each delta, write wc (all b128, coalesced)
  const int kl = (tid & 7) * 8;
#pragma unroll
  for (int p = 0; p < 2; p++) {
    int n = (tid >> 3) + p * 32;
    const float4* bp = (const float4*)(bw + (size_t)(n0 + n) * HIDDEN + kp0 * 8 + kl);
    float4 b0 = bp[0], b1 = bp[1];
    float bv[8] = {b0.x, b0.y, b0.z, b0.w, b1.x, b1.y, b1.z, b1.w};
#pragma unroll
    for (int d = 0; d < 4; d++) {
      short8v w = *(short8v*)&tile[d][n][kl];
      short8v o;
#pragma unroll
      for (int j = 0; j < 8; j++) o[j] = f2bf(bv[j] + bf2f(w[j]));
      *(short8v*)(wc + ((size_t)d * NTOT + n0 + n) * HIDDEN + kp0 * 8 + kl) = o;
    }
  }
}

// ---------------------------------------------------------------------------
// Kernel 4: grouped gathered GEMM. out[tok] = xb[tok] @ Wc[d]^T
// 128x128 tile, BK=32, 4 waves each owning a 64x64 quadrant (4x4 of
// 16x16x32 bf16 MFMA). XOR-swizzled LDS staging (seg^=(row>>1)&3) makes
// fragment ds_read_b128 conflict-free while keeping global_load_lds's
// linear lane->LDS mapping. Grid y indexes a compact tile table.
// ---------------------------------------------------------------------------
__global__ __launch_bounds__(256) void gemm_grouped(
    const short* __restrict__ xb, const short* __restrict__ wc,
    const int* __restrict__ token_list, const int* __restrict__ grp,
    float* __restrict__ out) {
  const int nt = grp[8];
  if ((int)blockIdx.y >= nt) return;
  const int te = grp[9 + blockIdx.y];
  const int d  = te & 3;
  const int rt = te >> 2;
  const int cnt   = grp[4 + d];
  const int start = grp[d];
  const int n0 = blockIdx.x * 128;

  __shared__ __align__(16) short As[128 * 32];
  __shared__ __align__(16) short Bs[128 * 32];
  __shared__ int toks[128];

  const int tid = threadIdx.x;
  if (tid < 128) {
    int r = rt * 128 + tid;
    if (r >= cnt) r = cnt - 1;          // clamp tail (stores guarded below)
    toks[tid] = token_list[start + r];
  }
  __syncthreads();

  const int wave = tid >> 6;
  const int lane = tid & 63;

  // staging: 512 units of 16B; unit u holds global (row=u>>2, seg=(u&3)^((u>>3)&3))
  const int u0  = wave * 128 + lane;
  const int rA0 = u0 >> 2;              // rA1 = rA0 + 16
  const int sw  = ((lane & 3) ^ ((lane >> 3) & 3)) * 8;  // swizzled k-seg (shorts)

  const short* gA0 = xb + (size_t)toks[rA0] * HIDDEN + sw;
  const short* gA1 = xb + (size_t)toks[rA0 + 16] * HIDDEN + sw;
  const short* wrow = wc + ((size_t)d * NTOT + n0) * HIDDEN;
  const short* gB0 = wrow + (size_t)rA0 * HIDDEN + sw;
  const short* gB1 = gB0 + 16 * HIDDEN;
  short* lA0 = As + (size_t)wave * 1024;  // wave-uniform base (+lane*16B implicit)
  short* lA1 = lA0 + 512;
  short* lB0 = Bs + (size_t)wave * 1024;
  short* lB1 = lB0 + 512;

  const int mrow = lane & 15;
  // fragment read: element (r, kseg s) lives at LDS unit r*4 + (s^((r>>1)&3));
  // r = 16*i + wm + mrow with wm,16*i multiples of 16 -> (r>>1)&3 == (mrow>>1)&3
  const int sx  = (((lane >> 4) ^ ((mrow >> 1) & 3))) * 8;
  const int wm  = (wave >> 1) * 64;
  const int wn  = (wave & 1) * 64;

  floatx4 acc[4][4];
#pragma unroll
  for (int i = 0; i < 4; i++)
#pragma unroll
    for (int j = 0; j < 4; j++) acc[i][j] = (floatx4){0.f, 0.f, 0.f, 0.f};

  for (int k0 = 0; k0 < HIDDEN; k0 += 32) {
    load_lds16(gA0 + k0, lA0);
    load_lds16(gA1 + k0, lA1);
    load_lds16(gB0 + k0, lB0);
    load_lds16(gB1 + k0, lB1);
    __syncthreads();   // compiler drains vmcnt before barrier

    bf16x8 a[4], b[4];
#pragma unroll
    for (int i = 0; i < 4; i++)
      a[i] = *(const bf16x8*)(As + (wm + i * 16 + mrow) * 32 + sx);
#pragma unroll
    for (int j = 0; j < 4; j++)
      b[j] = *(const bf16x8*)(Bs + (wn + j * 16 + mrow) * 32 + sx);
#pragma unroll
    for (int i = 0; i < 4; i++)
#pragma unroll
      for (int j = 0; j < 4; j++)
        acc[i][j] = __builtin_amdgcn_mfma_f32_16x16x32_bf16(a[i], b[j], acc[i][j], 0, 0, 0);
    __syncthreads();
  }

  // epilogue: C/D layout col = lane&15, row = (lane>>4)*4 + reg
  const int rbase = (lane >> 4) * 4;
  const int coll  = lane & 15;
#pragma unroll
  for (int i = 0; i < 4; i++) {
#pragma unroll
    for (int r = 0; r < 4; r++) {
      int m = wm + i * 16 + rbase + r;
      if (rt * 128 + m < cnt) {
        float* orow = out + (size_t)toks[m] * NTOT + n0 + wn + coll;
#pragma unroll
        for (int j = 0; j < 4; j++) orow[j * 16] = acc[i][j][r];
      }
    }
  }
}

// ---------------------------------------------------------------------------
extern "C" void kernel_launch(void* const* d_in, const int* in_sizes, int n_in,
                              void* d_out, int out_size, void* d_ws, size_t ws_size,
                              hipStream_t stream) {
  const float* x   = (const float*)d_in[0];
  const float* bw  = (const float*)d_in[1];
  const int*   qwq = (const int*)d_in[2];
  const int*   qwk = (const int*)d_in[3];
  const int*   qwv = (const int*)d_in[4];
  const int*   qzq = (const int*)d_in[5];
  const int*   qzk = (const int*)d_in[6];
  const int*   qzv = (const int*)d_in[7];
  const float* scq = (const float*)d_in[8];
  const float* sck = (const float*)d_in[9];
  const float* scv = (const float*)d_in[10];
  const int*   idx = (const int*)d_in[11];
  float* out = (float*)d_out;

  // workspace layout (needs ~235 MB)
  char* ws = (char*)d_ws;
  short* xb = (short*)ws;                                       // 33,554,432 B
  short* wc = (short*)(ws + (size_t)33554432);                  // 201,326,592 B
  int* token_list = (int*)(ws + (size_t)33554432 + 201326592);  // 16,384 B
  int* grp = token_list + TOKENS;                               // 256 B

  prep_tokens<<<1, 256, 0, stream>>>(idx, token_list, grp);
  cvt_x<<<(TOKENS * HIDDEN) / (256 * 8), 256, 0, stream>>>(x, xb);
  dim3 gc(HIDDEN / 64, NTOT / 64);  // (64, 96)
  combine_w<<<gc, 256, 0, stream>>>(bw, qwq, qwk, qwv, qzq, qzk, qzv, scq, sck, scv, wc);
  dim3 gg(NTOT / 128, MAXTILES);  // (48, 36)
  gemm_grouped<<<gg, 256, 0, stream>>>(xb, wc, token_list, grp, out);
}

// Round 3
// 583.858 us; speedup vs baseline: 1.2324x; 1.2144x over previous
//
#include <hip/hip_runtime.h>
#include <stdint.h>

// Problem constants (fixed by reference setup_inputs)
#define TOKENS 4096
#define HIDDEN 4096   // K
#define NQ     4096
#define NKV    1024
#define NTOT   6144   // NQ + 2*NKV
#define KPACK  512    // HIDDEN / 8
#define MAXTILES 36   // max sum_d ceil(cnt_d/128)

typedef __attribute__((ext_vector_type(8))) __bf16 bf16x8;
typedef __attribute__((ext_vector_type(8))) short short8v;
typedef __attribute__((ext_vector_type(4))) float floatx4;

// fp32 -> bf16 round-to-nearest-even (finite inputs only)
__device__ __forceinline__ short f2bf(float f) {
  union { float f; unsigned u; } v; v.f = f;
  unsigned r = v.u + 0x7fffu + ((v.u >> 16) & 1u);
  return (short)(r >> 16);
}

// async global->LDS, 16B per lane; LDS dest = wave-uniform base + lane*16
__device__ __forceinline__ void load_lds16(const void* g, void* l) {
  __builtin_amdgcn_global_load_lds((__attribute__((address_space(1))) void*)(g),
                                   (__attribute__((address_space(3))) void*)(l),
                                   16, 0, 0);
}

// ---------------------------------------------------------------------------
// Kernel 1: bucket tokens by delta index + build compact tile table.
// grp[0..3]=start, grp[4..7]=count, grp[8]=n_tiles, grp[9..9+nt)=d|(rt<<2).
// ---------------------------------------------------------------------------
__global__ __launch_bounds__(256) void prep_tokens(const int* __restrict__ idx,
                                                   int* __restrict__ token_list,
                                                   int* __restrict__ grp) {
  __shared__ int cnt[4], cur[4];
  const int tid = threadIdx.x;
  if (tid < 4) cnt[tid] = 0;
  __syncthreads();
  for (int t = tid; t < TOKENS; t += 256) {
    int d = idx[t];
    if ((unsigned)d < 4u) atomicAdd(&cnt[d], 1);
  }
  __syncthreads();
  if (tid == 0) {
    int s = 0, nt = 0;
    for (int d = 0; d < 4; d++) {
      cur[d] = s; grp[d] = s; grp[4 + d] = cnt[d]; s += cnt[d];
      int tiles = (cnt[d] + 127) >> 7;
      for (int rt = 0; rt < tiles; rt++) grp[9 + nt++] = d | (rt << 2);
    }
    grp[8] = nt;
  }
  __syncthreads();
  for (int t = tid; t < TOKENS; t += 256) {
    int d = idx[t];
    if ((unsigned)d < 4u) {
      int p = atomicAdd(&cur[d], 1);
      token_list[p] = t;
    }
  }
}

// ---------------------------------------------------------------------------
// Kernel 2: x fp32 -> bf16 (row-major (TOKENS, HIDDEN)); 8 elems/thread.
// ---------------------------------------------------------------------------
__global__ __launch_bounds__(256) void cvt_x(const float* __restrict__ x,
                                             short* __restrict__ xb) {
  size_t g = (size_t)blockIdx.x * 256 + threadIdx.x;
  size_t i = g * 8;
  float4 a = ((const float4*)(x + i))[0];
  float4 b = ((const float4*)(x + i))[1];
  short8v o;
  o[0] = f2bf(a.x); o[1] = f2bf(a.y); o[2] = f2bf(a.z); o[3] = f2bf(a.w);
  o[4] = f2bf(b.x); o[5] = f2bf(b.y); o[6] = f2bf(b.z); o[7] = f2bf(b.w);
  *(short8v*)(xb + i) = o;
}

// ---------------------------------------------------------------------------
// Kernel 3: Wc[d] (NTOT x HIDDEN bf16, B^T layout) = base + dequant(delta_d).
// Transpose raw int32s through LDS: ldsq[d][kp][n], stride 72 ints.
//  phase A write  (lane->n, fixed kp): bank (8*kp + n)%32 -> 2 lanes/bank, free
//  phase B read   (lane->(kp=t&7, n=t>>3)): bank (8*kp+n)%32 distinct -> free
// Phase B: base read ONCE per (n,k), d-loop innermost; wc stores 16B/lane,
// 8 lanes cover 128B contiguous per row. All global traffic coalesced.
// ---------------------------------------------------------------------------
__global__ __launch_bounds__(256) void combine_w(
    const float* __restrict__ bw,
    const int* __restrict__ qwq, const int* __restrict__ qwk, const int* __restrict__ qwv,
    const int* __restrict__ qzq, const int* __restrict__ qzk, const int* __restrict__ qzv,
    const float* __restrict__ scq, const float* __restrict__ sck, const float* __restrict__ scv,
    short* __restrict__ wc) {
  __shared__ int ldsq[4][8][72];
  __shared__ float zs[4][64], ss[4][64];
  const int tid = threadIdx.x;
  const int n0  = blockIdx.y * 64;
  const int kp0 = blockIdx.x * 8;   // k0 = kp0*8

  const int* qw; const int* qz; const float* sc; int Ns, nb;
  if (n0 < NQ)            { qw = qwq; qz = qzq; sc = scq; Ns = NQ;  nb = n0; }
  else if (n0 < NQ + NKV) { qw = qwk; qz = qzk; sc = sck; Ns = NKV; nb = n0 - NQ; }
  else                    { qw = qwv; qz = qzv; sc = scv; Ns = NKV; nb = n0 - NQ - NKV; }

  // zeros + scales: tid -> (d = tid>>6, n = tid&63)
  {
    int d = tid >> 6, n = tid & 63;
    int nn = nb + n;
    int z = (int)(((unsigned)qz[d * (Ns >> 3) + (nn >> 3)] >> ((nn & 7) * 4)) & 0xFu);
    zs[d][n] = (float)(z + 1);
    ss[d][n] = sc[d * Ns + nn];
  }

  // phase A: stage raw ints (coalesced along n; conflict-free LDS writes)
#pragma unroll
  for (int d = 0; d < 4; d++) {
#pragma unroll
    for (int p = 0; p < 2; p++) {
      int i  = tid + p * 256;
      int kp = i >> 6, n = i & 63;
      ldsq[d][kp][n] = qw[((size_t)d * KPACK + kp0 + kp) * Ns + nb + n];
    }
  }
  __syncthreads();

  // phase B: lane -> (kp = tid&7, n = tid>>3 + p*32); base once, d innermost
  const int kp = tid & 7;
#pragma unroll
  for (int p = 0; p < 2; p++) {
    int n = (tid >> 3) + p * 32;
    const float4* bp = (const float4*)(bw + (size_t)(n0 + n) * HIDDEN + (kp0 + kp) * 8);
    float4 b0 = bp[0], b1 = bp[1];
    float bv[8] = {b0.x, b0.y, b0.z, b0.w, b1.x, b1.y, b1.z, b1.w};
#pragma unroll
    for (int d = 0; d < 4; d++) {
      unsigned q32 = (unsigned)ldsq[d][kp][n];
      float z = zs[d][n], s = ss[d][n];
      short8v o;
#pragma unroll
      for (int j = 0; j < 8; j++)
        o[j] = f2bf(((float)((q32 >> (4 * j)) & 0xFu) - z) * s + bv[j]);
      *(short8v*)(wc + ((size_t)d * NTOT + n0 + n) * HIDDEN + (kp0 + kp) * 8) = o;
    }
  }
}

// ---------------------------------------------------------------------------
// Kernel 4: grouped gathered GEMM. out[tok] = xb[tok] @ Wc[d]^T
// 128x256 tile, BK=32, 4 waves each owning a 64x128 sub-tile (4x8 of
// 16x16x32 bf16 MFMA) -> LDS bytes/FLOP x0.75 vs 64x64 wave tile
// (the measured bottleneck: LDS pipe). XOR-swizzled staging keeps
// ds_read_b128 conflict-free under global_load_lds's linear lane map.
// ---------------------------------------------------------------------------
__global__ __launch_bounds__(256, 2) void gemm_grouped(
    const short* __restrict__ xb, const short* __restrict__ wc,
    const int* __restrict__ token_list, const int* __restrict__ grp,
    float* __restrict__ out) {
  const int nt = grp[8];
  if ((int)blockIdx.y >= nt) return;
  const int te = grp[9 + blockIdx.y];
  const int d  = te & 3;
  const int rt = te >> 2;
  const int cnt   = grp[4 + d];
  const int start = grp[d];
  const int n0 = blockIdx.x * 256;

  __shared__ __align__(16) short As[128 * 32];   // 8 KB
  __shared__ __align__(16) short Bs[256 * 32];   // 16 KB
  __shared__ int toks[128];

  const int tid = threadIdx.x;
  if (tid < 128) {
    int r = rt * 128 + tid;
    if (r >= cnt) r = cnt - 1;          // clamp tail (stores guarded below)
    toks[tid] = token_list[start + r];
  }
  __syncthreads();

  const int wave = tid >> 6;
  const int lane = tid & 63;

  // staging unit u (16B) holds global (row = u>>2, seg = (u&3)^((u>>3)&3));
  // chunk offsets are multiples of 64 units -> per-lane seg swizzle fixed:
  const int sw = ((lane & 3) ^ ((lane >> 3) & 3)) * 8;  // shorts

  // A: 512 units; wave w covers u = w*128 + {0,64} + lane
  const int arow0 = wave * 32 + (lane >> 2);            // row of unit w*128+lane
  const short* gA0 = xb + (size_t)toks[arow0] * HIDDEN + sw;
  const short* gA1 = xb + (size_t)toks[arow0 + 16] * HIDDEN + sw;
  short* lA0 = As + (size_t)wave * 1024;                // +lane*16B implicit
  short* lA1 = lA0 + 512;

  // B: 1024 units; wave w covers u = w*256 + {0,64,128,192} + lane
  const short* wrow = wc + ((size_t)d * NTOT + n0) * HIDDEN;
  const int brow0 = wave * 64 + (lane >> 2);
  const short* gB0 = wrow + (size_t)brow0 * HIDDEN + sw;
  const short* gB1 = gB0 + (size_t)16 * HIDDEN;
  const short* gB2 = gB0 + (size_t)32 * HIDDEN;
  const short* gB3 = gB0 + (size_t)48 * HIDDEN;
  short* lB0 = Bs + (size_t)wave * 2048;
  short* lB1 = lB0 + 512;
  short* lB2 = lB0 + 1024;
  short* lB3 = lB0 + 1536;

  const int mrow = lane & 15;
  // fragment read: (row r, kseg s) lives at unit r*4 + (s^((r>>1)&3));
  // r = mrow + mult-of-16 -> (r>>1)&3 == (mrow>>1)&3
  const int sx = (((lane >> 4) ^ ((mrow >> 1) & 3))) * 8;
  const int wm = (wave >> 1) * 64;
  const int wn = (wave & 1) * 128;

  floatx4 acc[4][8];
#pragma unroll
  for (int i = 0; i < 4; i++)
#pragma unroll
    for (int j = 0; j < 8; j++) acc[i][j] = (floatx4){0.f, 0.f, 0.f, 0.f};

  for (int k0 = 0; k0 < HIDDEN; k0 += 32) {
    load_lds16(gA0 + k0, lA0);
    load_lds16(gA1 + k0, lA1);
    load_lds16(gB0 + k0, lB0);
    load_lds16(gB1 + k0, lB1);
    load_lds16(gB2 + k0, lB2);
    load_lds16(gB3 + k0, lB3);
    __syncthreads();   // compiler drains vmcnt before barrier

    bf16x8 a[4], b[8];
#pragma unroll
    for (int i = 0; i < 4; i++)
      a[i] = *(const bf16x8*)(As + (wm + i * 16 + mrow) * 32 + sx);
#pragma unroll
    for (int j = 0; j < 8; j++)
      b[j] = *(const bf16x8*)(Bs + (wn + j * 16 + mrow) * 32 + sx);
#pragma unroll
    for (int i = 0; i < 4; i++)
#pragma unroll
      for (int j = 0; j < 8; j++)
        acc[i][j] = __builtin_amdgcn_mfma_f32_16x16x32_bf16(a[i], b[j], acc[i][j], 0, 0, 0);
    __syncthreads();
  }

  // epilogue: C/D layout col = lane&15, row = (lane>>4)*4 + reg
  const int rbase = (lane >> 4) * 4;
  const int coll  = lane & 15;
#pragma unroll
  for (int i = 0; i < 4; i++) {
#pragma unroll
    for (int r = 0; r < 4; r++) {
      int m = wm + i * 16 + rbase + r;
      if (rt * 128 + m < cnt) {
        float* orow = out + (size_t)toks[m] * NTOT + n0 + wn + coll;
#pragma unroll
        for (int j = 0; j < 8; j++) orow[j * 16] = acc[i][j][r];
      }
    }
  }
}

// ---------------------------------------------------------------------------
extern "C" void kernel_launch(void* const* d_in, const int* in_sizes, int n_in,
                              void* d_out, int out_size, void* d_ws, size_t ws_size,
                              hipStream_t stream) {
  const float* x   = (const float*)d_in[0];
  const float* bw  = (const float*)d_in[1];
  const int*   qwq = (const int*)d_in[2];
  const int*   qwk = (const int*)d_in[3];
  const int*   qwv = (const int*)d_in[4];
  const int*   qzq = (const int*)d_in[5];
  const int*   qzk = (const int*)d_in[6];
  const int*   qzv = (const int*)d_in[7];
  const float* scq = (const float*)d_in[8];
  const float* sck = (const float*)d_in[9];
  const float* scv = (const float*)d_in[10];
  const int*   idx = (const int*)d_in[11];
  float* out = (float*)d_out;

  // workspace layout (needs ~235 MB)
  char* ws = (char*)d_ws;
  short* xb = (short*)ws;                                       // 33,554,432 B
  short* wc = (short*)(ws + (size_t)33554432);                  // 201,326,592 B
  int* token_list = (int*)(ws + (size_t)33554432 + 201326592);  // 16,384 B
  int* grp = token_list + TOKENS;                               // 256 B

  prep_tokens<<<1, 256, 0, stream>>>(idx, token_list, grp);
  cvt_x<<<(TOKENS * HIDDEN) / (256 * 8), 256, 0, stream>>>(x, xb);
  dim3 gc(HIDDEN / 64, NTOT / 64);  // (64, 96)
  combine_w<<<gc, 256, 0, stream>>>(bw, qwq, qwk, qwv, qzq, qzk, qzv, scq, sck, scv, wc);
  dim3 gg(NTOT / 256, MAXTILES);  // (24, 36)
  gemm_grouped<<<gg, 256, 0, stream>>>(xb, wc, token_list, grp, out);
}